// Round 2
// baseline (232.433 us; speedup 1.0000x reference)
//
#include <hip/hip_runtime.h>

// LaneAttention: per-lane MLP score -> per-group(8) softmax -> weighted pool of
// concat(ht, info, future) into out[32768, 192] fp32.
//
// R1: phase-1 global reads were 256B-strided per lane (64 cache lines per wave
// instruction) -> request-bound at 2.4 TB/s. Now: block cooperatively stages
// its 256x64 input tile into LDS with fully coalesced float4 loads, computes
// the MLP from LDS. Rotate swizzle (feature c of row r at word r*64+((c+r)&63))
// makes per-row LDS reads conflict-free (2 lanes/bank) while keeping the W1
// index wave-uniform (scalar loads). ht staged+consumed, then buffer reused
// for info; phase 2 reads info from LDS, ht/fut from global (coalesced,
// L2-hot). prob moves between lanes by __shfl (LDS budget is exactly 64 KB).

__global__ __launch_bounds__(256) void lane_attn_kernel(
    const float* __restrict__ ht,     // [M,64]
    const float* __restrict__ info,   // [M,64]
    const float* __restrict__ fut,    // [M,64]
    const float* __restrict__ W1,     // [128,16]
    const float* __restrict__ b1,     // [16]
    const float* __restrict__ W2,     // [16]
    const float* __restrict__ b2,     // [1]
    const int*   __restrict__ seg,    // [M]
    float*       __restrict__ out)    // [N_GROUPS,192]
{
    __shared__ float tile[256 * 64];  // exactly 64 KB, rotate-swizzled

    const int t         = threadIdx.x;
    const int blockBase = blockIdx.x * 256;

    float h[16];
#pragma unroll
    for (int j = 0; j < 16; ++j) h[j] = b1[j];

    // ---------------- stage ht tile (coalesced) ----------------
    {
        const float4* src = (const float4*)ht + (size_t)blockBase * 16;
#pragma unroll
        for (int it = 0; it < 16; ++it) {
            const int f = it * 256 + t;          // float4 index in tile
            float4 v = src[f];
            const int r  = f >> 4;               // local row
            const int c0 = (f & 15) << 2;        // first feature of this float4
            const int rb = r * 64;
            tile[rb + ((c0 + 0 + r) & 63)] = v.x;
            tile[rb + ((c0 + 1 + r) & 63)] = v.y;
            tile[rb + ((c0 + 2 + r) & 63)] = v.z;
            tile[rb + ((c0 + 3 + r) & 63)] = v.w;
        }
    }
    __syncthreads();

    // ---------------- MLP: ht contribution (features 0..63) ----------------
    {
        const int rb = t * 64;
#pragma unroll 8
        for (int k = 0; k < 64; ++k) {
            const float x = tile[rb + ((k + t) & 63)];
#pragma unroll
            for (int j = 0; j < 16; ++j)
                h[j] = fmaf(x, W1[k * 16 + j], h[j]);
        }
    }
    __syncthreads();

    // ---------------- stage info tile (coalesced, reuse buffer) ------------
    {
        const float4* src = (const float4*)info + (size_t)blockBase * 16;
#pragma unroll
        for (int it = 0; it < 16; ++it) {
            const int f = it * 256 + t;
            float4 v = src[f];
            const int r  = f >> 4;
            const int c0 = (f & 15) << 2;
            const int rb = r * 64;
            tile[rb + ((c0 + 0 + r) & 63)] = v.x;
            tile[rb + ((c0 + 1 + r) & 63)] = v.y;
            tile[rb + ((c0 + 2 + r) & 63)] = v.z;
            tile[rb + ((c0 + 3 + r) & 63)] = v.w;
        }
    }
    __syncthreads();

    // ---------------- MLP: info contribution (features 64..127) ------------
    {
        const int rb = t * 64;
#pragma unroll 8
        for (int k = 0; k < 64; ++k) {
            const float x = tile[rb + ((k + t) & 63)];
#pragma unroll
            for (int j = 0; j < 16; ++j)
                h[j] = fmaf(x, W1[(64 + k) * 16 + j], h[j]);
        }
    }

    float score = b2[0];
#pragma unroll
    for (int j = 0; j < 16; ++j)
        score = fmaf(fmaxf(h[j], 0.0f), W2[j], score);

    // ---------------- softmax within each 8-lane subgroup ------------------
    float m = score;
    m = fmaxf(m, __shfl_xor(m, 1));
    m = fmaxf(m, __shfl_xor(m, 2));
    m = fmaxf(m, __shfl_xor(m, 4));
    float e = __expf(score - m);
    float s = e;
    s += __shfl_xor(s, 1);
    s += __shfl_xor(s, 2);
    s += __shfl_xor(s, 4);
    const float prob = e / s;

    // ---------------- phase 2: softmax-weighted pooling --------------------
    // Wave w pools local groups [8w, 8w+8): exactly the rows its own lanes
    // scored, so prob arrives by __shfl. info comes from LDS (still resident),
    // ht/fut from global (coalesced 256B rows, L2-hot).
    const int wave = t >> 6;
    const int c    = t & 63;
    for (int gg = 0; gg < 8; ++gg) {
        const int lr0 = wave * 64 + gg * 8;      // local row base of this group
        const int r0g = blockBase + lr0;         // global row base
        const int gid = seg[r0g];                // wave-uniform load
        float a0 = 0.0f, a1 = 0.0f, a2 = 0.0f;
#pragma unroll
        for (int i = 0; i < 8; ++i) {
            const float p  = __shfl(prob, gg * 8 + i);
            const int   lr = lr0 + i;
            const size_t rg = (size_t)(r0g + i) * 64;
            a0 = fmaf(p, ht[rg + c], a0);
            a1 = fmaf(p, tile[lr * 64 + ((c + lr) & 63)], a1);
            a2 = fmaf(p, fut[rg + c], a2);
        }
        float* o = out + (size_t)gid * 192;
        o[c]       = a0;
        o[64 + c]  = a1;
        o[128 + c] = a2;
    }
}

extern "C" void kernel_launch(void* const* d_in, const int* in_sizes, int n_in,
                              void* d_out, int out_size, void* d_ws, size_t ws_size,
                              hipStream_t stream) {
    const float* ht   = (const float*)d_in[0];
    const float* info = (const float*)d_in[1];
    const float* fut  = (const float*)d_in[2];
    const float* W1   = (const float*)d_in[3];
    const float* b1   = (const float*)d_in[4];
    const float* W2   = (const float*)d_in[5];
    const float* b2   = (const float*)d_in[6];
    const int*   seg  = (const int*)d_in[7];
    float*       out  = (float*)d_out;

    const int M = in_sizes[7];           // 262144 lanes
    const int blocks = M / 256;          // 1024

    lane_attn_kernel<<<blocks, 256, 0, stream>>>(ht, info, fut, W1, b1, W2, b2,
                                                 seg, out);
}

// Round 3
// 221.014 us; speedup vs baseline: 1.0517x; 1.0517x over previous
//
#include <hip/hip_runtime.h>

// LaneAttention: per-lane MLP score -> per-group(8) softmax -> weighted pool of
// concat(ht, info, future) into out[32768, 192] fp32.
//
// R2: R0/R1 were latency-exposure bound (VALUBusy ~14%, hbm ~25% of peak,
// occupancy <=38%): grid of 1024x256 supplied only 4 blocks/CU and barriers
// serialized each block. Now: single-wave 64-thread blocks, 4096 blocks
// (16 waves/CU supply), ZERO LDS, ZERO barriers. prob moves by __shfl.
// Access patterns identical to R0 (FETCH was already at the logical minimum;
// the phase-2 re-read of ht is L2-hot).

__global__ __launch_bounds__(64) void lane_attn_kernel(
    const float* __restrict__ ht,     // [M,64]
    const float* __restrict__ info,   // [M,64]
    const float* __restrict__ fut,    // [M,64]
    const float* __restrict__ W1,     // [128,16]
    const float* __restrict__ b1,     // [16]
    const float* __restrict__ W2,     // [16]
    const float* __restrict__ b2,     // [1]
    const int*   __restrict__ seg,    // [M]
    float*       __restrict__ out)    // [N_GROUPS,192]
{
    const int t    = threadIdx.x;     // 0..63, one wave
    const int base = blockIdx.x * 64; // first row of this wave's 64 rows
    const int lane = base + t;

    // ---------------- phase 1: per-lane MLP score ----------------
    // W1/b1 indices are wave-uniform -> scalar loads (SGPR operand on v_fma).
    float h[16];
#pragma unroll
    for (int j = 0; j < 16; ++j) h[j] = b1[j];

    const float4* htp = (const float4*)(ht   + (size_t)lane * 64);
    const float4* inp = (const float4*)(info + (size_t)lane * 64);

#pragma unroll 4
    for (int k4 = 0; k4 < 16; ++k4) {
        float4 v = htp[k4];
#pragma unroll
        for (int j = 0; j < 16; ++j) {
            h[j] = fmaf(v.x, W1[(k4 * 4 + 0) * 16 + j], h[j]);
            h[j] = fmaf(v.y, W1[(k4 * 4 + 1) * 16 + j], h[j]);
            h[j] = fmaf(v.z, W1[(k4 * 4 + 2) * 16 + j], h[j]);
            h[j] = fmaf(v.w, W1[(k4 * 4 + 3) * 16 + j], h[j]);
        }
    }
#pragma unroll 4
    for (int k4 = 0; k4 < 16; ++k4) {
        float4 v = inp[k4];
#pragma unroll
        for (int j = 0; j < 16; ++j) {
            h[j] = fmaf(v.x, W1[(64 + k4 * 4 + 0) * 16 + j], h[j]);
            h[j] = fmaf(v.y, W1[(64 + k4 * 4 + 1) * 16 + j], h[j]);
            h[j] = fmaf(v.z, W1[(64 + k4 * 4 + 2) * 16 + j], h[j]);
            h[j] = fmaf(v.w, W1[(64 + k4 * 4 + 3) * 16 + j], h[j]);
        }
    }

    float score = b2[0];
#pragma unroll
    for (int j = 0; j < 16; ++j)
        score = fmaf(fmaxf(h[j], 0.0f), W2[j], score);

    // ---------------- softmax within each 8-lane subgroup ----------------
    float m = score;
    m = fmaxf(m, __shfl_xor(m, 1));
    m = fmaxf(m, __shfl_xor(m, 2));
    m = fmaxf(m, __shfl_xor(m, 4));
    float e = __expf(score - m);
    float s = e;
    s += __shfl_xor(s, 1);
    s += __shfl_xor(s, 2);
    s += __shfl_xor(s, 4);
    const float prob = e / s;   // lane t holds prob of row base+t

    // ---------------- phase 2: softmax-weighted pooling --------------------
    // The wave pools its own 8 groups. Thread c covers column c of each array.
    // Row reads are coalesced 256B; ht/info are L1/L2-hot from phase 1.
    const int c = t;
    for (int gg = 0; gg < 8; ++gg) {
        const int r0  = base + gg * 8;
        const int gid = seg[r0];          // wave-uniform
        float a0 = 0.0f, a1 = 0.0f, a2 = 0.0f;
#pragma unroll
        for (int i = 0; i < 8; ++i) {
            const float  p = __shfl(prob, gg * 8 + i);
            const size_t r = (size_t)(r0 + i) * 64;
            a0 = fmaf(p, ht[r + c],   a0);
            a1 = fmaf(p, info[r + c], a1);
            a2 = fmaf(p, fut[r + c],  a2);
        }
        float* o = out + (size_t)gid * 192;
        o[c]       = a0;
        o[64 + c]  = a1;
        o[128 + c] = a2;
    }
}

extern "C" void kernel_launch(void* const* d_in, const int* in_sizes, int n_in,
                              void* d_out, int out_size, void* d_ws, size_t ws_size,
                              hipStream_t stream) {
    const float* ht   = (const float*)d_in[0];
    const float* info = (const float*)d_in[1];
    const float* fut  = (const float*)d_in[2];
    const float* W1   = (const float*)d_in[3];
    const float* b1   = (const float*)d_in[4];
    const float* W2   = (const float*)d_in[5];
    const float* b2   = (const float*)d_in[6];
    const int*   seg  = (const int*)d_in[7];
    float*       out  = (float*)d_out;

    const int M = in_sizes[7];           // 262144 lanes
    const int blocks = M / 64;           // 4096 single-wave blocks

    lane_attn_kernel<<<blocks, 64, 0, stream>>>(ht, info, fut, W1, b1, W2, b2,
                                                seg, out);
}